// Round 3
// baseline (1167.901 us; speedup 1.0000x reference)
//
#include <hip/hip_runtime.h>
#include <cstdint>
#include <cstddef>

// ---------------------------------------------------------------------------
// CrossAttention2D: out = softmax((rope(XqWq^T) rope(XkWk^T)^T)/8) (XvWv^T) Wo^T
// B=4, N=48*48=2304, E=1024, H=16, D=64. bf16 MFMA, fp32 accum.
// R3: transpose-free attention. Compute S^T = K Q^T (swapped operands, same
//     loads). S^T's C-layout == the B-operand layout of mfma_f32_16x16x16f16,
//     so P feeds PV directly from registers: no LDS, no shuffles, no barriers
//     in the K-loop. O^T accumulated; V and P in f16. K-frags double-buffered.
// ---------------------------------------------------------------------------

typedef __bf16 bf16x8 __attribute__((ext_vector_type(8)));
typedef __bf16 bf16x4 __attribute__((ext_vector_type(4)));
typedef _Float16 f16x4 __attribute__((ext_vector_type(4)));
typedef float f32x4 __attribute__((ext_vector_type(4)));

constexpr int Bc = 4, Hc = 16, Nc = 2304, Ec = 1024, WPc = 48;
constexpr int BNc = Bc * Nc;  // 9216

__device__ __forceinline__ f32x4 mfma16(bf16x8 a, bf16x8 b, f32x4 c) {
  return __builtin_amdgcn_mfma_f32_16x16x32_bf16(a, b, c, 0, 0, 0);
}

#define GPTR(p) ((const __attribute__((address_space(1))) void*)(p))
#define LPTR(p) ((__attribute__((address_space(3))) void*)(p))

// --------------------------- fp32 -> bf16 convert ---------------------------
__global__ __launch_bounds__(256) void cvt_bf16(const float* __restrict__ s,
                                                __bf16* __restrict__ d, int n) {
  int i = (blockIdx.x * 256 + threadIdx.x) * 8;
  if (i >= n) return;
  float4 f0 = *(const float4*)(s + i);
  float4 f1 = *(const float4*)(s + i + 4);
  bf16x8 v;
  v[0] = (__bf16)f0.x; v[1] = (__bf16)f0.y; v[2] = (__bf16)f0.z; v[3] = (__bf16)f0.w;
  v[4] = (__bf16)f1.x; v[5] = (__bf16)f1.y; v[6] = (__bf16)f1.z; v[7] = (__bf16)f1.w;
  *(bf16x8*)(d + i) = v;
}

// --------------------------- GEMM: C = A @ W^T + bias -----------------------
// Tile 128x128, BK=32, 4 waves x 64x64. global_load_lds width-16 staging.
// Epilogues: 0 = fp32 +bias; 1 = RoPE+scale -> bf16 (b,h,n,d); 2 = f16 V^T (b,h,d,n)
enum { EPI_F32 = 0, EPI_ROPE = 1, EPI_VT = 2 };

template <int EPI>
__global__ __launch_bounds__(256) void gemm_nt(const __bf16* __restrict__ A,
                                               const __bf16* __restrict__ W,
                                               const float* __restrict__ bias,
                                               void* __restrict__ Out, float scale) {
  constexpr int K = Ec;
  __shared__ __align__(16) __bf16 As[128 * 32];
  __shared__ __align__(16) __bf16 Bs[128 * 32];

  const int t = threadIdx.x;
  const int tn = blockIdx.x & 7;   // 8 col tiles
  const int tm = blockIdx.x >> 3;  // 72 row tiles
  const int lane = t & 63, wave = t >> 6;
  const int wm = wave & 1, wn = wave >> 1;
  const int quad = lane >> 4, l15 = lane & 15;

  const int rowInC = lane >> 2, colC = (lane & 3) * 8;
  const __bf16* Ab = A + (size_t)(tm * 128) * K;
  const __bf16* Wb = W + (size_t)(tn * 128) * K;

  f32x4 zero = {0.f, 0.f, 0.f, 0.f};
  f32x4 acc[4][4];
  for (int i = 0; i < 4; ++i)
    for (int j = 0; j < 4; ++j) acc[i][j] = zero;

  for (int kk = 0; kk < K; kk += 32) {
#pragma unroll
    for (int tch = 0; tch < 2; ++tch) {
      const int ch = wave * 2 + tch;        // 0..7 -> rows ch*16..+15
      const int row = ch * 16 + rowInC;
      __builtin_amdgcn_global_load_lds(GPTR(Ab + (size_t)row * K + kk + colC),
                                       LPTR(As + ch * 512), 16, 0, 0);
      __builtin_amdgcn_global_load_lds(GPTR(Wb + (size_t)row * K + kk + colC),
                                       LPTR(Bs + ch * 512), 16, 0, 0);
    }
    __syncthreads();

    bf16x8 af[4], bfg[4];
#pragma unroll
    for (int i = 0; i < 4; ++i)
      af[i] = *(const bf16x8*)(As + (wm * 64 + i * 16 + l15) * 32 + quad * 8);
#pragma unroll
    for (int j = 0; j < 4; ++j)
      bfg[j] = *(const bf16x8*)(Bs + (wn * 64 + j * 16 + l15) * 32 + quad * 8);
#pragma unroll
    for (int i = 0; i < 4; ++i)
#pragma unroll
      for (int j = 0; j < 4; ++j) acc[i][j] = mfma16(af[i], bfg[j], acc[i][j]);
    __syncthreads();
  }

  const int m0 = tm * 128 + wm * 64;
  const int nb0 = tn * 128 + wn * 64;

  if (EPI == EPI_F32) {
    float* C = (float*)Out;
#pragma unroll
    for (int j = 0; j < 4; ++j) {
      const int n = nb0 + j * 16 + l15;
      const float bi = bias[n];
#pragma unroll
      for (int i = 0; i < 4; ++i) {
        const int m = m0 + i * 16 + quad * 4;
#pragma unroll
        for (int r = 0; r < 4; ++r) C[(size_t)(m + r) * Ec + n] = acc[i][j][r] + bi;
      }
    }
  } else if (EPI == EPI_ROPE) {
    __bf16* O = (__bf16*)Out;
    const int h = nb0 >> 6;  // one head per 64-col wave tile
    float bj[4];
#pragma unroll
    for (int j = 0; j < 4; ++j) bj[j] = bias[nb0 + j * 16 + l15];
    const float f = exp2f(-(float)l15 * 0.8304820237218406f);
#pragma unroll
    for (int i = 0; i < 4; ++i) {
#pragma unroll
      for (int r = 0; r < 4; ++r) {
        const int m = m0 + i * 16 + quad * 4 + r;
        const int b = m / Nc;
        const int ntok = m - b * Nc;
        const int ph = ntok / WPc, pw = ntok - (ntok / WPc) * WPc;
        float sh, ch, sw, cw;
        __sincosf((float)ph * f, &sh, &ch);
        __sincosf((float)pw * f, &sw, &cw);
        const float x0 = acc[i][0][r] + bj[0];
        const float x1 = acc[i][1][r] + bj[1];
        const float x2 = acc[i][2][r] + bj[2];
        const float x3 = acc[i][3][r] + bj[3];
        __bf16* Op = O + ((size_t)(b * Hc + h) * Nc + ntok) * 64;
        Op[l15]      = (__bf16)((x0 * ch - x1 * sh) * scale);
        Op[16 + l15] = (__bf16)((x1 * ch + x0 * sh) * scale);
        Op[32 + l15] = (__bf16)((x2 * cw - x3 * sw) * scale);
        Op[48 + l15] = (__bf16)((x3 * cw + x2 * sw) * scale);
      }
    }
  } else {  // EPI_VT : Vt[(b*H+h)*64 + d][ntok]  (f16)
    _Float16* Vt = (_Float16*)Out;
    const int h = nb0 >> 6;
#pragma unroll
    for (int i = 0; i < 4; ++i) {
      const int m = m0 + i * 16 + quad * 4;
      const int b = m / Nc;
      const int ntok = m - b * Nc;  // multiple of 4; rows r stay in same b
#pragma unroll
      for (int j = 0; j < 4; ++j) {
        const int d = j * 16 + l15;
        const float bi = bias[nb0 + j * 16 + l15];
        f16x4 v;
#pragma unroll
        for (int r = 0; r < 4; ++r) v[r] = (_Float16)(acc[i][j][r] + bi);
        *(f16x4*)(Vt + ((size_t)(b * Hc + h) * 64 + d) * Nc + ntok) = v;
      }
    }
  }
}

// --------------------------- flash attention (transpose-free) ---------------
// grid (64 bh, 36 q-tiles), 4 waves/block, 16 Q-rows/wave, TK=64.
// S^T = K Q^T via 16x16x32 bf16 (A=K, B=Q: identical loads to S=QK^T).
// S^T C-layout [k=quad*4+r][q=l15] == B-layout of mfma_f32_16x16x16f16, so
// P = exp2(S^T) feeds PV directly from registers. O^T = V^T P accumulated in
// C-layout. No max-subtraction (|logit| <~ 8 << fp32/f16 range). No LDS,
// no cross-lane ops, no barriers in the loop. K-frags double-buffered.
__global__ __launch_bounds__(256) void attn(const __bf16* __restrict__ Qh,
                                            const __bf16* __restrict__ Kh,
                                            const _Float16* __restrict__ Vt,
                                            __bf16* __restrict__ Om) {
  const int bh = blockIdx.x;
  const int t = threadIdx.x, wave = t >> 6, lane = t & 63;
  const int quad = lane >> 4, l15 = lane & 15;
  const int qbase = blockIdx.y * 64 + wave * 16;

  const __bf16* Qb = Qh + ((size_t)bh * Nc + qbase + l15) * 64 + quad * 8;
  const bf16x8 bq0 = *(const bf16x8*)(Qb);
  const bf16x8 bq1 = *(const bf16x8*)(Qb + 32);

  const __bf16* Kbh = Kh + ((size_t)bh * Nc + l15) * 64 + quad * 8;
  const _Float16* Vbh = Vt + ((size_t)bh * 64 + l15) * Nc + quad * 4;

  const f32x4 zero = {0.f, 0.f, 0.f, 0.f};
  f32x4 oacc[4] = {zero, zero, zero, zero};  // O^T[d=dt*16+quad*4+r][q=l15]
  float lsum[4] = {0.f, 0.f, 0.f, 0.f};

  // K A-frags for tile 0 (double-buffered one tile ahead)
  bf16x8 ak[2][4];
#pragma unroll
  for (int ks = 0; ks < 2; ++ks)
#pragma unroll
    for (int ct = 0; ct < 4; ++ct)
      ak[ks][ct] = *(const bf16x8*)(Kbh + (size_t)(ct * 16) * 64 + ks * 32);

  for (int kt = 0; kt < Nc / 64; ++kt) {
    const int kr0 = kt * 64;
    const int krn = (kt + 1 == Nc / 64) ? 0 : (kt + 1) * 64;  // wrap: harmless

    // current tile's V A-frags + next tile's K A-frags: issue all loads first
    f16x4 av[4][4];
#pragma unroll
    for (int dt = 0; dt < 4; ++dt)
#pragma unroll
      for (int ct = 0; ct < 4; ++ct)
        av[dt][ct] = *(const f16x4*)(Vbh + (size_t)(dt * 16) * Nc + kr0 + ct * 16);
    bf16x8 akn[2][4];
#pragma unroll
    for (int ks = 0; ks < 2; ++ks)
#pragma unroll
      for (int ct = 0; ct < 4; ++ct)
        akn[ks][ct] = *(const bf16x8*)(Kbh + (size_t)(krn + ct * 16) * 64 + ks * 32);

    // ---- S^T = K Q^T ----
    f32x4 sacc[4] = {zero, zero, zero, zero};
#pragma unroll
    for (int ct = 0; ct < 4; ++ct) sacc[ct] = mfma16(ak[0][ct], bq0, sacc[ct]);
#pragma unroll
    for (int ct = 0; ct < 4; ++ct) sacc[ct] = mfma16(ak[1][ct], bq1, sacc[ct]);

    // ---- P = exp2(S^T), pack to f16 B-frags, per-lane partial sums ----
    f16x4 pf[4];
#pragma unroll
    for (int ct = 0; ct < 4; ++ct) {
#pragma unroll
      for (int r = 0; r < 4; ++r) {
        const float p = exp2f(sacc[ct][r]);
        lsum[ct] += p;
        pf[ct][r] = (_Float16)p;
      }
    }

    // ---- O^T += V^T P  (A = V^T frag, B = P frag, direct from regs) ----
#pragma unroll
    for (int ct = 0; ct < 4; ++ct)
#pragma unroll
      for (int dt = 0; dt < 4; ++dt)
        oacc[dt] = __builtin_amdgcn_mfma_f32_16x16x16f16(av[dt][ct], pf[ct],
                                                         oacc[dt], 0, 0, 0);

    // rotate K double-buffer
#pragma unroll
    for (int ks = 0; ks < 2; ++ks)
#pragma unroll
      for (int ct = 0; ct < 4; ++ct) ak[ks][ct] = akn[ks][ct];
  }

  // ---- epilogue: quad-reduce row sum (q=l15), normalize, store O ----
  float s = (lsum[0] + lsum[1]) + (lsum[2] + lsum[3]);
  s += __shfl_xor(s, 16);
  s += __shfl_xor(s, 32);
  const float rinv = 1.0f / s;

  const int b = bh >> 4, h = bh & 15;
  __bf16* Op = Om + ((size_t)b * Nc + qbase + l15) * Ec + h * 64 + quad * 4;
#pragma unroll
  for (int dt = 0; dt < 4; ++dt) {
    bf16x4 o;
#pragma unroll
    for (int r = 0; r < 4; ++r) o[r] = (__bf16)(oacc[dt][r] * rinv);
    *(bf16x4*)(Op + dt * 16) = o;
  }
}

// ---------------------------------------------------------------------------
extern "C" void kernel_launch(void* const* d_in, const int* in_sizes, int n_in,
                              void* d_out, int out_size, void* d_ws, size_t ws_size,
                              hipStream_t stream) {
  const float* q  = (const float*)d_in[0];
  const float* k  = (const float*)d_in[1];
  const float* v  = (const float*)d_in[2];
  const float* Wq = (const float*)d_in[3];
  const float* bq = (const float*)d_in[4];
  const float* Wk = (const float*)d_in[5];
  const float* bk = (const float*)d_in[6];
  const float* Wv = (const float*)d_in[7];
  const float* bv = (const float*)d_in[8];
  const float* Wo = (const float*)d_in[9];
  const float* bo = (const float*)d_in[10];
  float* out = (float*)d_out;

  const size_t EE = (size_t)Ec * Ec;          // 1 M elems
  const size_t BNE = (size_t)BNc * Ec;        // 9.4 M elems

  // workspace carve (~102 MB with aliasing)
  char* w = (char*)d_ws;
  __bf16* Wqb = (__bf16*)w; w += EE * 2;
  __bf16* Wkb = (__bf16*)w; w += EE * 2;
  __bf16* Wvb = (__bf16*)w; w += EE * 2;
  __bf16* Wob = (__bf16*)w; w += EE * 2;
  __bf16* qb  = (__bf16*)w; w += BNE * 2;
  __bf16* kb  = (__bf16*)w; w += BNE * 2;
  __bf16* vb  = (__bf16*)w; w += BNE * 2;
  __bf16* Qhp = (__bf16*)w; w += BNE * 2;
  __bf16* Khp = (__bf16*)w; w += BNE * 2;
  _Float16* Vtp = (_Float16*)kb;  // kb dead after K-GEMM; V-GEMM writes here
  __bf16* Omp = qb;               // qb dead after Q-GEMM; attn writes here

  const dim3 blk(256);
  const dim3 gCvtW(EE / 8 / 256);    // 512
  const dim3 gCvtA(BNE / 8 / 256);   // 4608
  const dim3 gGemm(8 * (BNc / 128)); // 576
  const dim3 gAttn(Bc * Hc, Nc / 64);

  cvt_bf16<<<gCvtW, blk, 0, stream>>>(Wq, Wqb, (int)EE);
  cvt_bf16<<<gCvtW, blk, 0, stream>>>(Wk, Wkb, (int)EE);
  cvt_bf16<<<gCvtW, blk, 0, stream>>>(Wv, Wvb, (int)EE);
  cvt_bf16<<<gCvtW, blk, 0, stream>>>(Wo, Wob, (int)EE);
  cvt_bf16<<<gCvtA, blk, 0, stream>>>(q, qb, (int)BNE);
  cvt_bf16<<<gCvtA, blk, 0, stream>>>(k, kb, (int)BNE);
  cvt_bf16<<<gCvtA, blk, 0, stream>>>(v, vb, (int)BNE);

  const float qscale = 0.125f * 1.44269504088896340736f;  // 1/sqrt(64) * log2(e)

  gemm_nt<EPI_ROPE><<<gGemm, blk, 0, stream>>>(qb, Wqb, bq, Qhp, qscale);
  gemm_nt<EPI_ROPE><<<gGemm, blk, 0, stream>>>(kb, Wkb, bk, Khp, 1.0f);
  gemm_nt<EPI_VT>  <<<gGemm, blk, 0, stream>>>(vb, Wvb, bv, Vtp, 1.0f);

  attn<<<gAttn, blk, 0, stream>>>(Qhp, Khp, Vtp, Omp);

  gemm_nt<EPI_F32><<<gGemm, blk, 0, stream>>>(Omp, Wob, bo, out, 1.0f);
}

// Round 4
// 522.751 us; speedup vs baseline: 2.2341x; 2.2341x over previous
//
#include <hip/hip_runtime.h>
#include <cstdint>
#include <cstddef>

// ---------------------------------------------------------------------------
// CrossAttention2D: out = softmax((rope(XqWq^T) rope(XkWk^T)^T)/8) (XvWv^T) Wo^T
// B=4, N=48*48=2304, E=1024, H=16, D=64. bf16 MFMA, fp32 accum.
// R4: attention restructured GEMM-style: K/V tiles staged cooperatively into
//     double-buffered LDS via global_load_lds (zero VGPR cost), shared by all
//     4 waves; 32 Q-rows/wave (128/block). Register-direct S^T->PV kept.
//     K/V global layouts XOR-swizzled at producer epilogues so unpadded LDS
//     reads are conflict-free (global_load_lds forbids padding).
// ---------------------------------------------------------------------------

typedef __bf16 bf16x8 __attribute__((ext_vector_type(8)));
typedef __bf16 bf16x4 __attribute__((ext_vector_type(4)));
typedef _Float16 f16x4 __attribute__((ext_vector_type(4)));
typedef float f32x4 __attribute__((ext_vector_type(4)));

constexpr int Bc = 4, Hc = 16, Nc = 2304, Ec = 1024, WPc = 48;
constexpr int BNc = Bc * Nc;  // 9216

__device__ __forceinline__ f32x4 mfma16(bf16x8 a, bf16x8 b, f32x4 c) {
  return __builtin_amdgcn_mfma_f32_16x16x32_bf16(a, b, c, 0, 0, 0);
}

#define GPTR(p) ((const __attribute__((address_space(1))) void*)(p))
#define LPTR(p) ((__attribute__((address_space(3))) void*)(p))

// --------------------------- fp32 -> bf16 convert ---------------------------
__global__ __launch_bounds__(256) void cvt_bf16(const float* __restrict__ s,
                                                __bf16* __restrict__ d, int n) {
  int i = (blockIdx.x * 256 + threadIdx.x) * 8;
  if (i >= n) return;
  float4 f0 = *(const float4*)(s + i);
  float4 f1 = *(const float4*)(s + i + 4);
  bf16x8 v;
  v[0] = (__bf16)f0.x; v[1] = (__bf16)f0.y; v[2] = (__bf16)f0.z; v[3] = (__bf16)f0.w;
  v[4] = (__bf16)f1.x; v[5] = (__bf16)f1.y; v[6] = (__bf16)f1.z; v[7] = (__bf16)f1.w;
  *(bf16x8*)(d + i) = v;
}

// --------------------------- GEMM: C = A @ W^T + bias -----------------------
// Tile 128x128, BK=32, 4 waves x 64x64. global_load_lds width-16 staging.
// EPI_F32: fp32 +bias. EPI_ROPE: RoPE+scale -> bf16 (b,h,n,d), SWZ=1 XOR-
// swizzles 16B chunks (chunk ^ (n&7)) for attn K staging. EPI_VT: f16 V^T
// (b,h,d,n) with 8B chunks swizzled (chunk ^ (d&15)) within 64-token segs.
enum { EPI_F32 = 0, EPI_ROPE = 1, EPI_VT = 2 };

template <int EPI, int SWZ>
__global__ __launch_bounds__(256) void gemm_nt(const __bf16* __restrict__ A,
                                               const __bf16* __restrict__ W,
                                               const float* __restrict__ bias,
                                               void* __restrict__ Out, float scale) {
  constexpr int K = Ec;
  __shared__ __align__(16) __bf16 As[128 * 32];
  __shared__ __align__(16) __bf16 Bs[128 * 32];

  const int t = threadIdx.x;
  const int tn = blockIdx.x & 7;   // 8 col tiles
  const int tm = blockIdx.x >> 3;  // 72 row tiles
  const int lane = t & 63, wave = t >> 6;
  const int wm = wave & 1, wn = wave >> 1;
  const int quad = lane >> 4, l15 = lane & 15;

  const int rowInC = lane >> 2, colC = (lane & 3) * 8;
  const __bf16* Ab = A + (size_t)(tm * 128) * K;
  const __bf16* Wb = W + (size_t)(tn * 128) * K;

  f32x4 zero = {0.f, 0.f, 0.f, 0.f};
  f32x4 acc[4][4];
  for (int i = 0; i < 4; ++i)
    for (int j = 0; j < 4; ++j) acc[i][j] = zero;

  for (int kk = 0; kk < K; kk += 32) {
#pragma unroll
    for (int tch = 0; tch < 2; ++tch) {
      const int ch = wave * 2 + tch;        // 0..7 -> rows ch*16..+15
      const int row = ch * 16 + rowInC;
      __builtin_amdgcn_global_load_lds(GPTR(Ab + (size_t)row * K + kk + colC),
                                       LPTR(As + ch * 512), 16, 0, 0);
      __builtin_amdgcn_global_load_lds(GPTR(Wb + (size_t)row * K + kk + colC),
                                       LPTR(Bs + ch * 512), 16, 0, 0);
    }
    __syncthreads();

    bf16x8 af[4], bfg[4];
#pragma unroll
    for (int i = 0; i < 4; ++i)
      af[i] = *(const bf16x8*)(As + (wm * 64 + i * 16 + l15) * 32 + quad * 8);
#pragma unroll
    for (int j = 0; j < 4; ++j)
      bfg[j] = *(const bf16x8*)(Bs + (wn * 64 + j * 16 + l15) * 32 + quad * 8);
#pragma unroll
    for (int i = 0; i < 4; ++i)
#pragma unroll
      for (int j = 0; j < 4; ++j) acc[i][j] = mfma16(af[i], bfg[j], acc[i][j]);
    __syncthreads();
  }

  const int m0 = tm * 128 + wm * 64;
  const int nb0 = tn * 128 + wn * 64;

  if (EPI == EPI_F32) {
    float* C = (float*)Out;
#pragma unroll
    for (int j = 0; j < 4; ++j) {
      const int n = nb0 + j * 16 + l15;
      const float bi = bias[n];
#pragma unroll
      for (int i = 0; i < 4; ++i) {
        const int m = m0 + i * 16 + quad * 4;
#pragma unroll
        for (int r = 0; r < 4; ++r) C[(size_t)(m + r) * Ec + n] = acc[i][j][r] + bi;
      }
    }
  } else if (EPI == EPI_ROPE) {
    __bf16* O = (__bf16*)Out;
    const int h = nb0 >> 6;  // one head per 64-col wave tile
    float bj[4];
#pragma unroll
    for (int j = 0; j < 4; ++j) bj[j] = bias[nb0 + j * 16 + l15];
    const float f = exp2f(-(float)l15 * 0.8304820237218406f);
    const int lo3 = l15 & 7, hi8 = l15 >> 3;  // within-chunk offset / chunk bit
#pragma unroll
    for (int i = 0; i < 4; ++i) {
#pragma unroll
      for (int r = 0; r < 4; ++r) {
        const int m = m0 + i * 16 + quad * 4 + r;
        const int b = m / Nc;
        const int ntok = m - b * Nc;
        const int ph = ntok / WPc, pw = ntok - (ntok / WPc) * WPc;
        float sh, ch, sw, cw;
        __sincosf((float)ph * f, &sh, &ch);
        __sincosf((float)pw * f, &sw, &cw);
        const float x0 = acc[i][0][r] + bj[0];
        const float x1 = acc[i][1][r] + bj[1];
        const float x2 = acc[i][2][r] + bj[2];
        const float x3 = acc[i][3][r] + bj[3];
        __bf16* Op = O + ((size_t)(b * Hc + h) * Nc + ntok) * 64;
        const int n7 = SWZ ? (ntok & 7) : 0;
        // element d stored at chunk (d>>3)^n7, offset d&7
        Op[(((0 + hi8) ^ n7) << 3) | lo3] = (__bf16)((x0 * ch - x1 * sh) * scale);
        Op[(((2 + hi8) ^ n7) << 3) | lo3] = (__bf16)((x1 * ch + x0 * sh) * scale);
        Op[(((4 + hi8) ^ n7) << 3) | lo3] = (__bf16)((x2 * cw - x3 * sw) * scale);
        Op[(((6 + hi8) ^ n7) << 3) | lo3] = (__bf16)((x3 * cw + x2 * sw) * scale);
      }
    }
  } else {  // EPI_VT : f16 V^T rows d, 8B chunks swizzled within 64-tok segs
    _Float16* Vt = (_Float16*)Out;
    const int h = nb0 >> 6;
#pragma unroll
    for (int i = 0; i < 4; ++i) {
      const int m = m0 + i * 16 + quad * 4;
      const int b = m / Nc;
      const int ntok = m - b * Nc;  // multiple of 4; rows r stay in same b
      const int seg = ntok >> 6;
      const int cw = (ntok >> 2) & 15;
#pragma unroll
      for (int j = 0; j < 4; ++j) {
        const int d = j * 16 + l15;
        const float bi = bias[nb0 + j * 16 + l15];
        f16x4 v;
#pragma unroll
        for (int r = 0; r < 4; ++r) v[r] = (_Float16)(acc[i][j][r] + bi);
        const int off = seg * 64 + (((cw ^ l15) & 15) << 2);  // d&15 == l15
        *(f16x4*)(Vt + ((size_t)(b * Hc + h) * 64 + d) * Nc + off) = v;
      }
    }
  }
}

// --------------------------- flash attention (R4) ---------------------------
// grid (64 bh, 18 q-tiles), 4 waves/block. Q-tile 128 (32 rows/wave, 2
// subtiles). K-tile 64 staged to LDS (K 8KB bf16 + V^T 8KB f16, x2 dbuf).
// S^T = K Q^T (16x16x32 bf16); P = exp2(S^T) feeds PV (16x16x16 f16) directly
// from registers; O^T accumulated. No max-subtraction (|logit| small). LDS
// reads use the producer-baked XOR swizzle -> <=2-way conflicts.
constexpr int TQ = 128, TK = 64, NT = Nc / TK;  // 18 q-tiles, 36 k-tiles

__global__ __launch_bounds__(256) void attn(const __bf16* __restrict__ Qh,
                                            const __bf16* __restrict__ Kg,
                                            const _Float16* __restrict__ Vg,
                                            __bf16* __restrict__ Om) {
  const int bh = blockIdx.x;
  const int t = threadIdx.x, wave = t >> 6, lane = t & 63;
  const int quad = lane >> 4, l15 = lane & 15;

  __shared__ __align__(16) __bf16 Kls[2][TK * 64];
  __shared__ __align__(16) _Float16 Vls[2][TK * 64];

  const int qbase = blockIdx.y * TQ + wave * 32;
  bf16x8 bq[2][2];
#pragma unroll
  for (int s = 0; s < 2; ++s)
#pragma unroll
    for (int ks = 0; ks < 2; ++ks)
      bq[s][ks] = *(const bf16x8*)(Qh + ((size_t)bh * Nc + qbase + s * 16 + l15) * 64 +
                                   ks * 32 + quad * 8);

  const __bf16* Kbh = Kg + (size_t)bh * Nc * 64;
  const _Float16* Vbh = Vg + (size_t)bh * 64 * Nc;

  const f32x4 zero = {0.f, 0.f, 0.f, 0.f};
  f32x4 oacc[2][4] = {{zero, zero, zero, zero}, {zero, zero, zero, zero}};
  float lsum[2][4] = {{0.f, 0.f, 0.f, 0.f}, {0.f, 0.f, 0.f, 0.f}};

  const int vrow = lane >> 3, vcol = (lane & 7) * 8;  // V DMA lane mapping

#define STAGE(kt, buf)                                                          \
  {                                                                             \
    _Pragma("unroll") for (int i = 0; i < 2; ++i) {                             \
      const int ch = wave * 2 + i;                                              \
      __builtin_amdgcn_global_load_lds(                                         \
          GPTR(Kbh + (size_t)(kt) * TK * 64 + ch * 512 + lane * 8),             \
          LPTR(&Kls[buf][ch * 512]), 16, 0, 0);                                 \
    }                                                                           \
    _Pragma("unroll") for (int i = 0; i < 2; ++i) {                             \
      const int ch = wave * 2 + i;                                              \
      const int d = ch * 8 + vrow;                                              \
      __builtin_amdgcn_global_load_lds(                                         \
          GPTR(Vbh + (size_t)d * Nc + (kt) * 64 + vcol),                        \
          LPTR(&Vls[buf][ch * 512]), 16, 0, 0);                                 \
    }                                                                           \
  }

  STAGE(0, 0);
  __syncthreads();

  for (int kt = 0; kt < NT; ++kt) {
    const int buf = kt & 1;
    if (kt + 1 < NT) STAGE(kt + 1, buf ^ 1);

    // ---- S^T = K Q^T (A = K frags from LDS, B = Q frags in regs) ----
    f32x4 sacc[2][4] = {{zero, zero, zero, zero}, {zero, zero, zero, zero}};
#pragma unroll
    for (int ks = 0; ks < 2; ++ks) {
#pragma unroll
      for (int ct = 0; ct < 4; ++ct) {
        const bf16x8 ak = *(const bf16x8*)(
            &Kls[buf][(ct * 16 + l15) * 64 + (((ks * 4 + quad) ^ (l15 & 7)) << 3)]);
        sacc[0][ct] = mfma16(ak, bq[0][ks], sacc[0][ct]);
        sacc[1][ct] = mfma16(ak, bq[1][ks], sacc[1][ct]);
      }
    }

    // ---- P = exp2(S^T), pack f16 B-frags, per-lane partial sums ----
    f16x4 pf[2][4];
#pragma unroll
    for (int s = 0; s < 2; ++s)
#pragma unroll
      for (int ct = 0; ct < 4; ++ct)
#pragma unroll
        for (int r = 0; r < 4; ++r) {
          const float p = exp2f(sacc[s][ct][r]);
          lsum[s][ct] += p;
          pf[s][ct][r] = (_Float16)p;
        }

    // ---- O^T += V^T P (A = V^T frags from LDS, B = P frags in regs) ----
#pragma unroll
    for (int ct = 0; ct < 4; ++ct) {
#pragma unroll
      for (int dt = 0; dt < 4; ++dt) {
        const f16x4 av = *(const f16x4*)(
            &Vls[buf][(dt * 16 + l15) * 64 + (((ct * 4 + quad) ^ l15) << 2)]);
        oacc[0][dt] = __builtin_amdgcn_mfma_f32_16x16x16f16(av, pf[0][ct], oacc[0][dt], 0, 0, 0);
        oacc[1][dt] = __builtin_amdgcn_mfma_f32_16x16x16f16(av, pf[1][ct], oacc[1][dt], 0, 0, 0);
      }
    }
    __syncthreads();
  }

  // ---- epilogue: quad-reduce row sums, normalize, store O ----
  const int b = bh >> 4, h = bh & 15;
#pragma unroll
  for (int s = 0; s < 2; ++s) {
    float sm = (lsum[s][0] + lsum[s][1]) + (lsum[s][2] + lsum[s][3]);
    sm += __shfl_xor(sm, 16);
    sm += __shfl_xor(sm, 32);
    const float rinv = 1.0f / sm;
    __bf16* Op = Om + ((size_t)b * Nc + qbase + s * 16 + l15) * Ec + h * 64 + quad * 4;
#pragma unroll
    for (int dt = 0; dt < 4; ++dt) {
      bf16x4 o;
#pragma unroll
      for (int r = 0; r < 4; ++r) o[r] = (__bf16)(oacc[s][dt][r] * rinv);
      *(bf16x4*)(Op + dt * 16) = o;
    }
  }
#undef STAGE
}

// ---------------------------------------------------------------------------
extern "C" void kernel_launch(void* const* d_in, const int* in_sizes, int n_in,
                              void* d_out, int out_size, void* d_ws, size_t ws_size,
                              hipStream_t stream) {
  const float* q  = (const float*)d_in[0];
  const float* k  = (const float*)d_in[1];
  const float* v  = (const float*)d_in[2];
  const float* Wq = (const float*)d_in[3];
  const float* bq = (const float*)d_in[4];
  const float* Wk = (const float*)d_in[5];
  const float* bk = (const float*)d_in[6];
  const float* Wv = (const float*)d_in[7];
  const float* bv = (const float*)d_in[8];
  const float* Wo = (const float*)d_in[9];
  const float* bo = (const float*)d_in[10];
  float* out = (float*)d_out;

  const size_t EE = (size_t)Ec * Ec;          // 1 M elems
  const size_t BNE = (size_t)BNc * Ec;        // 9.4 M elems

  // workspace carve (~102 MB with aliasing)
  char* w = (char*)d_ws;
  __bf16* Wqb = (__bf16*)w; w += EE * 2;
  __bf16* Wkb = (__bf16*)w; w += EE * 2;
  __bf16* Wvb = (__bf16*)w; w += EE * 2;
  __bf16* Wob = (__bf16*)w; w += EE * 2;
  __bf16* qb  = (__bf16*)w; w += BNE * 2;
  __bf16* kb  = (__bf16*)w; w += BNE * 2;
  __bf16* vb  = (__bf16*)w; w += BNE * 2;
  __bf16* Qhp = (__bf16*)w; w += BNE * 2;
  __bf16* Khp = (__bf16*)w; w += BNE * 2;   // XOR-swizzled 16B chunks
  _Float16* Vtp = (_Float16*)kb;  // kb dead after K-GEMM; swizzled 8B chunks
  __bf16* Omp = qb;               // qb dead after Q-GEMM; attn writes here

  const dim3 blk(256);
  const dim3 gCvtW(EE / 8 / 256);    // 512
  const dim3 gCvtA(BNE / 8 / 256);   // 4608
  const dim3 gGemm(8 * (BNc / 128)); // 576
  const dim3 gAttn(Bc * Hc, Nc / TQ);

  cvt_bf16<<<gCvtW, blk, 0, stream>>>(Wq, Wqb, (int)EE);
  cvt_bf16<<<gCvtW, blk, 0, stream>>>(Wk, Wkb, (int)EE);
  cvt_bf16<<<gCvtW, blk, 0, stream>>>(Wv, Wvb, (int)EE);
  cvt_bf16<<<gCvtW, blk, 0, stream>>>(Wo, Wob, (int)EE);
  cvt_bf16<<<gCvtA, blk, 0, stream>>>(q, qb, (int)BNE);
  cvt_bf16<<<gCvtA, blk, 0, stream>>>(k, kb, (int)BNE);
  cvt_bf16<<<gCvtA, blk, 0, stream>>>(v, vb, (int)BNE);

  const float qscale = 0.125f * 1.44269504088896340736f;  // 1/sqrt(64) * log2(e)

  gemm_nt<EPI_ROPE, 0><<<gGemm, blk, 0, stream>>>(qb, Wqb, bq, Qhp, qscale);
  gemm_nt<EPI_ROPE, 1><<<gGemm, blk, 0, stream>>>(kb, Wkb, bk, Khp, 1.0f);
  gemm_nt<EPI_VT, 0>  <<<gGemm, blk, 0, stream>>>(vb, Wvb, bv, Vtp, 1.0f);

  attn<<<gAttn, blk, 0, stream>>>(Qhp, Khp, Vtp, Omp);

  gemm_nt<EPI_F32, 0><<<gGemm, blk, 0, stream>>>(Omp, Wob, bo, out, 1.0f);
}

// Round 5
// 481.163 us; speedup vs baseline: 2.4272x; 1.0864x over previous
//
#include <hip/hip_runtime.h>
#include <cstdint>
#include <cstddef>

// ---------------------------------------------------------------------------
// CrossAttention2D: out = softmax((rope(XqWq^T) rope(XkWk^T)^T)/8) (XvWv^T) Wo^T
// B=4, N=48*48=2304, E=1024, H=16, D=64. bf16 MFMA, fp32 accum.
// R5: attn row-sums via ones-MFMA (removes 32 v_add_f32/iter + epilogue
//     shuffles), kt-loop unrolled x2 (compile-time LDS buffer). Q+K
//     projections merged into one GEMM (A and epilogue selected per column
//     half, wave-uniform).
// ---------------------------------------------------------------------------

typedef __bf16 bf16x8 __attribute__((ext_vector_type(8)));
typedef __bf16 bf16x4 __attribute__((ext_vector_type(4)));
typedef _Float16 f16x4 __attribute__((ext_vector_type(4)));
typedef float f32x4 __attribute__((ext_vector_type(4)));

constexpr int Bc = 4, Hc = 16, Nc = 2304, Ec = 1024, WPc = 48;
constexpr int BNc = Bc * Nc;  // 9216

__device__ __forceinline__ f32x4 mfma16(bf16x8 a, bf16x8 b, f32x4 c) {
  return __builtin_amdgcn_mfma_f32_16x16x32_bf16(a, b, c, 0, 0, 0);
}
__device__ __forceinline__ f32x4 mfmah(f16x4 a, f16x4 b, f32x4 c) {
  return __builtin_amdgcn_mfma_f32_16x16x16f16(a, b, c, 0, 0, 0);
}

#define GPTR(p) ((const __attribute__((address_space(1))) void*)(p))
#define LPTR(p) ((__attribute__((address_space(3))) void*)(p))

// --------------------------- fp32 -> bf16 convert ---------------------------
__global__ __launch_bounds__(256) void cvt_bf16(const float* __restrict__ s,
                                                __bf16* __restrict__ d, int n) {
  int i = (blockIdx.x * 256 + threadIdx.x) * 8;
  if (i >= n) return;
  float4 f0 = *(const float4*)(s + i);
  float4 f1 = *(const float4*)(s + i + 4);
  bf16x8 v;
  v[0] = (__bf16)f0.x; v[1] = (__bf16)f0.y; v[2] = (__bf16)f0.z; v[3] = (__bf16)f0.w;
  v[4] = (__bf16)f1.x; v[5] = (__bf16)f1.y; v[6] = (__bf16)f1.z; v[7] = (__bf16)f1.w;
  *(bf16x8*)(d + i) = v;
}

// ---------------- shared GEMM core: 128x128 tile, BK=32, 4 waves ------------
#define GEMM_CORE(APTR, WPTR, KDIM)                                             \
  __shared__ __align__(16) __bf16 As[128 * 32];                                 \
  __shared__ __align__(16) __bf16 Bs[128 * 32];                                 \
  const int t = threadIdx.x;                                                    \
  const int lane = t & 63, wave = t >> 6;                                       \
  const int wm = wave & 1, wn = wave >> 1;                                      \
  const int quad = lane >> 4, l15 = lane & 15;                                  \
  const int rowInC = lane >> 2, colC = (lane & 3) * 8;                          \
  const __bf16* Ab = (APTR) + (size_t)(tm * 128) * (KDIM);                      \
  const __bf16* Wb = (WPTR) + (size_t)(tn * 128) * (KDIM);                      \
  f32x4 zero = {0.f, 0.f, 0.f, 0.f};                                            \
  f32x4 acc[4][4];                                                              \
  for (int i = 0; i < 4; ++i)                                                   \
    for (int j = 0; j < 4; ++j) acc[i][j] = zero;                               \
  for (int kk = 0; kk < (KDIM); kk += 32) {                                     \
    _Pragma("unroll") for (int tch = 0; tch < 2; ++tch) {                       \
      const int ch = wave * 2 + tch;                                            \
      const int row = ch * 16 + rowInC;                                         \
      __builtin_amdgcn_global_load_lds(GPTR(Ab + (size_t)row * (KDIM) + kk + colC), \
                                       LPTR(As + ch * 512), 16, 0, 0);          \
      __builtin_amdgcn_global_load_lds(GPTR(Wb + (size_t)row * (KDIM) + kk + colC), \
                                       LPTR(Bs + ch * 512), 16, 0, 0);          \
    }                                                                           \
    __syncthreads();                                                            \
    bf16x8 af[4], bfg[4];                                                       \
    _Pragma("unroll") for (int i = 0; i < 4; ++i)                               \
        af[i] = *(const bf16x8*)(As + (wm * 64 + i * 16 + l15) * 32 + quad * 8);\
    _Pragma("unroll") for (int j = 0; j < 4; ++j)                               \
        bfg[j] = *(const bf16x8*)(Bs + (wn * 64 + j * 16 + l15) * 32 + quad * 8);\
    _Pragma("unroll") for (int i = 0; i < 4; ++i)                               \
      _Pragma("unroll") for (int j = 0; j < 4; ++j)                             \
        acc[i][j] = mfma16(af[i], bfg[j], acc[i][j]);                           \
    __syncthreads();                                                            \
  }                                                                             \
  const int m0 = tm * 128 + wm * 64;                                            \
  const int nb0 = tn * 128 + wn * 64;

// ---------------- GEMM 1: fused Q+K projection + RoPE + head pack -----------
// Col tiles 0..7 -> Q (A = qb, scale, no swizzle); 8..15 -> K (A = qb + BNE
// = kb, unit scale, 16B-chunk XOR swizzle). All selects are block-uniform.
__global__ __launch_bounds__(256) void gemm_qk(const __bf16* __restrict__ qkb,
                                               const __bf16* __restrict__ Wqk,
                                               const float* __restrict__ bq,
                                               const float* __restrict__ bk,
                                               __bf16* __restrict__ Qhp,
                                               __bf16* __restrict__ Khp,
                                               float qscale) {
  const int tn = blockIdx.x & 15;   // 16 col tiles over 2048
  const int tm = blockIdx.x >> 4;   // 72 row tiles
  const int proj = tn >> 3;         // 0 = Q, 1 = K (block-uniform)
  const __bf16* Asel = qkb + (size_t)proj * BNc * Ec;
  GEMM_CORE(Asel, Wqk, Ec)

  const int h = (nb0 >> 6) & 15;
  const float scale = proj ? 1.0f : qscale;
  __bf16* O = proj ? Khp : Qhp;
  const float* bb = proj ? bk : bq;
  float bj[4];
#pragma unroll
  for (int j = 0; j < 4; ++j) bj[j] = bb[(nb0 + j * 16 + l15) & 1023];
  const float f = exp2f(-(float)l15 * 0.8304820237218406f);
  const int lo3 = l15 & 7, hi8 = l15 >> 3;
#pragma unroll
  for (int i = 0; i < 4; ++i) {
#pragma unroll
    for (int r = 0; r < 4; ++r) {
      const int m = m0 + i * 16 + quad * 4 + r;
      const int b = m / Nc;
      const int ntok = m - b * Nc;
      const int ph = ntok / WPc, pw = ntok - (ntok / WPc) * WPc;
      float sh, ch, sw, cw;
      __sincosf((float)ph * f, &sh, &ch);
      __sincosf((float)pw * f, &sw, &cw);
      const float x0 = acc[i][0][r] + bj[0];
      const float x1 = acc[i][1][r] + bj[1];
      const float x2 = acc[i][2][r] + bj[2];
      const float x3 = acc[i][3][r] + bj[3];
      __bf16* Op = O + ((size_t)(b * Hc + h) * Nc + ntok) * 64;
      const int n7 = proj ? (ntok & 7) : 0;
      Op[(((0 + hi8) ^ n7) << 3) | lo3] = (__bf16)((x0 * ch - x1 * sh) * scale);
      Op[(((2 + hi8) ^ n7) << 3) | lo3] = (__bf16)((x1 * ch + x0 * sh) * scale);
      Op[(((4 + hi8) ^ n7) << 3) | lo3] = (__bf16)((x2 * cw - x3 * sw) * scale);
      Op[(((6 + hi8) ^ n7) << 3) | lo3] = (__bf16)((x3 * cw + x2 * sw) * scale);
    }
  }
}

// ---------------- GEMM 2: V projection -> f16 V^T (b,h,d,n), swizzled -------
__global__ __launch_bounds__(256) void gemm_v(const __bf16* __restrict__ A,
                                              const __bf16* __restrict__ Wv,
                                              const float* __restrict__ bv,
                                              _Float16* __restrict__ Vt) {
  const int tn = blockIdx.x & 7;
  const int tm = blockIdx.x >> 3;
  GEMM_CORE(A, Wv, Ec)

  const int h = nb0 >> 6;
#pragma unroll
  for (int i = 0; i < 4; ++i) {
    const int m = m0 + i * 16 + quad * 4;
    const int b = m / Nc;
    const int ntok = m - b * Nc;
    const int seg = ntok >> 6;
    const int cw = (ntok >> 2) & 15;
#pragma unroll
    for (int j = 0; j < 4; ++j) {
      const int d = j * 16 + l15;
      const float bi = bv[nb0 + j * 16 + l15];
      f16x4 v;
#pragma unroll
      for (int r = 0; r < 4; ++r) v[r] = (_Float16)(acc[i][j][r] + bi);
      const int off = seg * 64 + (((cw ^ l15) & 15) << 2);
      *(f16x4*)(Vt + ((size_t)(b * Hc + h) * 64 + d) * Nc + off) = v;
    }
  }
}

// ---------------- GEMM 3: output projection, fp32 + bias --------------------
__global__ __launch_bounds__(256) void gemm_out(const __bf16* __restrict__ A,
                                                const __bf16* __restrict__ Wo,
                                                const float* __restrict__ bo,
                                                float* __restrict__ C) {
  const int tn = blockIdx.x & 7;
  const int tm = blockIdx.x >> 3;
  GEMM_CORE(A, Wo, Ec)

#pragma unroll
  for (int j = 0; j < 4; ++j) {
    const int n = nb0 + j * 16 + l15;
    const float bi = bo[n];
#pragma unroll
    for (int i = 0; i < 4; ++i) {
      const int m = m0 + i * 16 + quad * 4;
#pragma unroll
      for (int r = 0; r < 4; ++r) C[(size_t)(m + r) * Ec + n] = acc[i][j][r] + bi;
    }
  }
}

// --------------------------- flash attention (R5) ---------------------------
constexpr int TQ = 128, TK = 64, NT = Nc / TK;  // 18 q-tiles, 36 k-tiles

__global__ __launch_bounds__(256) void attn(const __bf16* __restrict__ Qh,
                                            const __bf16* __restrict__ Kg,
                                            const _Float16* __restrict__ Vg,
                                            __bf16* __restrict__ Om) {
  const int bh = blockIdx.x;
  const int t = threadIdx.x, wave = t >> 6, lane = t & 63;
  const int quad = lane >> 4, l15 = lane & 15;

  __shared__ __align__(16) __bf16 Kls[2][TK * 64];
  __shared__ __align__(16) _Float16 Vls[2][TK * 64];

  const int qbase = blockIdx.y * TQ + wave * 32;
  bf16x8 bq[2][2];
#pragma unroll
  for (int s = 0; s < 2; ++s)
#pragma unroll
    for (int ks = 0; ks < 2; ++ks)
      bq[s][ks] = *(const bf16x8*)(Qh + ((size_t)bh * Nc + qbase + s * 16 + l15) * 64 +
                                   ks * 32 + quad * 8);

  const __bf16* Kbh = Kg + (size_t)bh * Nc * 64;
  const _Float16* Vbh = Vg + (size_t)bh * 64 * Nc;

  const f32x4 zero = {0.f, 0.f, 0.f, 0.f};
  f32x4 oacc[2][4] = {{zero, zero, zero, zero}, {zero, zero, zero, zero}};
  f32x4 osum[2] = {zero, zero};
  const f16x4 fones = {(_Float16)1.f, (_Float16)1.f, (_Float16)1.f, (_Float16)1.f};

  const int vrow = lane >> 3, vcol = (lane & 7) * 8;

#define STAGE(kt, buf)                                                          \
  {                                                                             \
    _Pragma("unroll") for (int i = 0; i < 2; ++i) {                             \
      const int ch = wave * 2 + i;                                              \
      __builtin_amdgcn_global_load_lds(                                         \
          GPTR(Kbh + (size_t)(kt) * TK * 64 + ch * 512 + lane * 8),             \
          LPTR(&Kls[buf][ch * 512]), 16, 0, 0);                                 \
    }                                                                           \
    _Pragma("unroll") for (int i = 0; i < 2; ++i) {                             \
      const int ch = wave * 2 + i;                                              \
      const int d = ch * 8 + vrow;                                              \
      __builtin_amdgcn_global_load_lds(                                         \
          GPTR(Vbh + (size_t)d * Nc + (kt) * 64 + vcol),                        \
          LPTR(&Vls[buf][ch * 512]), 16, 0, 0);                                 \
    }                                                                           \
  }

#define COMPUTE(BUF)                                                            \
  {                                                                             \
    f32x4 sacc[2][4] = {{zero, zero, zero, zero}, {zero, zero, zero, zero}};    \
    _Pragma("unroll") for (int ks = 0; ks < 2; ++ks) {                          \
      _Pragma("unroll") for (int ct = 0; ct < 4; ++ct) {                        \
        const bf16x8 ak = *(const bf16x8*)(&Kls[BUF][(ct * 16 + l15) * 64 +     \
            (((ks * 4 + quad) ^ (l15 & 7)) << 3)]);                             \
        sacc[0][ct] = mfma16(ak, bq[0][ks], sacc[0][ct]);                       \
        sacc[1][ct] = mfma16(ak, bq[1][ks], sacc[1][ct]);                       \
      }                                                                         \
    }                                                                           \
    f16x4 pf[2][4];                                                             \
    _Pragma("unroll") for (int s = 0; s < 2; ++s)                               \
      _Pragma("unroll") for (int ct = 0; ct < 4; ++ct)                          \
        _Pragma("unroll") for (int r = 0; r < 4; ++r)                           \
          pf[s][ct][r] = (_Float16)exp2f(sacc[s][ct][r]);                       \
    _Pragma("unroll") for (int ct = 0; ct < 4; ++ct) {                          \
      _Pragma("unroll") for (int dt = 0; dt < 4; ++dt) {                        \
        const f16x4 av = *(const f16x4*)(&Vls[BUF][(dt * 16 + l15) * 64 +       \
            (((ct * 4 + quad) ^ l15) << 2)]);                                   \
        oacc[0][dt] = mfmah(av, pf[0][ct], oacc[0][dt]);                        \
        oacc[1][dt] = mfmah(av, pf[1][ct], oacc[1][dt]);                        \
      }                                                                         \
      osum[0] = mfmah(fones, pf[0][ct], osum[0]);                               \
      osum[1] = mfmah(fones, pf[1][ct], osum[1]);                               \
    }                                                                           \
  }

  STAGE(0, 0);
  __syncthreads();

  for (int kt = 0; kt < NT; kt += 2) {
    STAGE(kt + 1, 1);
    COMPUTE(0)
    __syncthreads();
    if (kt + 2 < NT) STAGE(kt + 2, 0);
    COMPUTE(1)
    __syncthreads();
  }

  // ---- epilogue: rinv from ones-MFMA (all regs equal), normalize, store ----
  const int b = bh >> 4, h = bh & 15;
#pragma unroll
  for (int s = 0; s < 2; ++s) {
    const float rinv = 1.0f / osum[s][0];
    __bf16* Op = Om + ((size_t)b * Nc + qbase + s * 16 + l15) * Ec + h * 64 + quad * 4;
#pragma unroll
    for (int dt = 0; dt < 4; ++dt) {
      bf16x4 o;
#pragma unroll
      for (int r = 0; r < 4; ++r) o[r] = (__bf16)(oacc[s][dt][r] * rinv);
      *(bf16x4*)(Op + dt * 16) = o;
    }
  }
#undef STAGE
#undef COMPUTE
}

// ---------------------------------------------------------------------------
extern "C" void kernel_launch(void* const* d_in, const int* in_sizes, int n_in,
                              void* d_out, int out_size, void* d_ws, size_t ws_size,
                              hipStream_t stream) {
  const float* q  = (const float*)d_in[0];
  const float* k  = (const float*)d_in[1];
  const float* v  = (const float*)d_in[2];
  const float* Wq = (const float*)d_in[3];
  const float* bq = (const float*)d_in[4];
  const float* Wk = (const float*)d_in[5];
  const float* bk = (const float*)d_in[6];
  const float* Wv = (const float*)d_in[7];
  const float* bv = (const float*)d_in[8];
  const float* Wo = (const float*)d_in[9];
  const float* bo = (const float*)d_in[10];
  float* out = (float*)d_out;

  const size_t EE = (size_t)Ec * Ec;          // 1 M elems
  const size_t BNE = (size_t)BNc * Ec;        // 9.4 M elems

  // workspace carve (~102 MB with aliasing). qb and kb MUST be adjacent:
  // gemm_qk indexes A as qb + proj*BNE.
  char* w = (char*)d_ws;
  __bf16* Wqkb = (__bf16*)w; w += 2 * EE * 2;  // W_q rows | W_k rows (2048x1024)
  __bf16* Wvb  = (__bf16*)w; w += EE * 2;
  __bf16* Wob  = (__bf16*)w; w += EE * 2;
  __bf16* qb   = (__bf16*)w; w += BNE * 2;
  __bf16* kb   = (__bf16*)w; w += BNE * 2;    // == qb + BNE
  __bf16* vb   = (__bf16*)w; w += BNE * 2;
  __bf16* Qhp  = (__bf16*)w; w += BNE * 2;
  __bf16* Khp  = (__bf16*)w; w += BNE * 2;    // XOR-swizzled 16B chunks
  _Float16* Vtp = (_Float16*)kb;  // kb dead after gemm_qk; gemm_v writes here
  __bf16* Omp = qb;               // qb dead after gemm_qk; attn writes here

  const dim3 blk(256);
  const dim3 gCvtW(EE / 8 / 256);     // 512
  const dim3 gCvtA(BNE / 8 / 256);    // 4608
  const dim3 gQK(16 * (BNc / 128));   // 1152
  const dim3 gG(8 * (BNc / 128));     // 576
  const dim3 gAttn(Bc * Hc, Nc / TQ);

  cvt_bf16<<<gCvtW, blk, 0, stream>>>(Wq, Wqkb, (int)EE);
  cvt_bf16<<<gCvtW, blk, 0, stream>>>(Wk, Wqkb + EE, (int)EE);
  cvt_bf16<<<gCvtW, blk, 0, stream>>>(Wv, Wvb, (int)EE);
  cvt_bf16<<<gCvtW, blk, 0, stream>>>(Wo, Wob, (int)EE);
  cvt_bf16<<<gCvtA, blk, 0, stream>>>(q, qb, (int)BNE);
  cvt_bf16<<<gCvtA, blk, 0, stream>>>(k, kb, (int)BNE);
  cvt_bf16<<<gCvtA, blk, 0, stream>>>(v, vb, (int)BNE);

  const float qscale = 0.125f * 1.44269504088896340736f;  // 1/sqrt(64) * log2(e)

  gemm_qk<<<gQK, blk, 0, stream>>>(qb, Wqkb, bq, bk, Qhp, Khp, qscale);
  gemm_v<<<gG, blk, 0, stream>>>(vb, Wvb, bv, Vtp);
  attn<<<gAttn, blk, 0, stream>>>(Qhp, Khp, Vtp, Omp);
  gemm_out<<<gG, blk, 0, stream>>>(Omp, Wob, bo, out);
}